// Round 1
// baseline (110.116 us; speedup 1.0000x reference)
//
#include <hip/hip_runtime.h>
#include <hip/hip_bf16.h>

// HarmonicOscillatorOrbitals: out[b,i,j] = exp(-s^2/2) * H_j(s), s = x[b,i]*k
// x: (65536, 32, 1) fp32; omega_kernel: (1,1) fp32; out: (65536, 32, 32) fp32.
// One thread per (b,i) row; 32 outputs per thread written as 8x float4.
// Memory-bound: ~268 MB write + 8 MB read.

#define N_HERM 32

__global__ __launch_bounds__(256) void hoo_kernel(
    const float* __restrict__ x,
    const float* __restrict__ omega,
    float* __restrict__ out,
    int n_rows)
{
    int tid = blockIdx.x * blockDim.x + threadIdx.x;
    if (tid >= n_rows) return;

    const float k = omega[0];                 // broadcast, L2-cached
    const float s = x[tid] * k;               // coalesced load
    const float env = expf(-0.5f * (s * s));  // gaussian envelope
    const float twox = 2.0f * s;

    float vals[N_HERM];
    // H_0 = 1, H_1 = 2x, H_k = 2x*H_{k-1} - 2(k-1)*H_{k-2}
    float hm2 = 1.0f;
    float hm1 = twox;
    vals[0] = env * hm2;
    vals[1] = env * hm1;
#pragma unroll
    for (int j = 2; j < N_HERM; ++j) {
        const float c = 2.0f * (float)(j - 1);
        const float h = twox * hm1 - c * hm2;
        hm2 = hm1;
        hm1 = h;
        vals[j] = env * h;
    }

    // 32 consecutive floats per thread -> 8 x float4 stores (128 B/thread).
    float4* orow = reinterpret_cast<float4*>(out + (size_t)tid * N_HERM);
#pragma unroll
    for (int q = 0; q < 8; ++q) {
        orow[q] = make_float4(vals[4 * q + 0], vals[4 * q + 1],
                              vals[4 * q + 2], vals[4 * q + 3]);
    }
}

extern "C" void kernel_launch(void* const* d_in, const int* in_sizes, int n_in,
                              void* d_out, int out_size, void* d_ws, size_t ws_size,
                              hipStream_t stream) {
    const float* x     = (const float*)d_in[0];
    const float* omega = (const float*)d_in[1];
    float* out         = (float*)d_out;

    const int n_rows = in_sizes[0];  // 65536 * 32 * 1 = 2,097,152

    const int block = 256;
    const int grid = (n_rows + block - 1) / block;
    hoo_kernel<<<grid, block, 0, stream>>>(x, omega, out, n_rows);
}

// Round 2
// 77.198 us; speedup vs baseline: 1.4264x; 1.4264x over previous
//
#include <hip/hip_runtime.h>
#include <hip/hip_bf16.h>

// HarmonicOscillatorOrbitals: out[b,i,j] = exp(-s^2/2) * H_j(s), s = x[b,i]*k
// x: (65536, 32, 1) fp32; out: (65536, 32, 32) fp32.
//
// Layout: 8 threads per row ("quads"); thread (row, q) computes H_{4q..4q+3}
// and stores ONE float4. Lane->address mapping is exactly contiguous:
// addr = 16 B * (global linear tid), so each wave store covers 1 KB of
// consecutive bytes (vs the previous version's 128 B-strided lanes that ran
// at 2.5 TB/s). Recurrence is recomputed per quad-thread (<=28 extra FMAs,
// negligible vs the 268 MB write bound).

__global__ __launch_bounds__(256) void hoo_kernel(
    const float* __restrict__ x,
    const float* __restrict__ omega,
    float4* __restrict__ out4,
    int n_rows)
{
    const int tid  = threadIdx.x;
    const int row  = blockIdx.x * 32 + (tid >> 3);  // 32 rows per block
    const int quad = tid & 7;                       // which 4-column group
    if (row >= n_rows) return;

    const float k = omega[0];
    const float s = x[row] * k;                     // 8-way shared, L1-cached
    const float env  = expf(-0.5f * (s * s));
    const float twox = 2.0f * s;

    // Rolling window of the last 4 Hermite values, statically indexed.
    // H_0=1, H_1=2x, H_k = 2x*H_{k-1} - 2(k-1)*H_{k-2}
    float h0 = 1.0f;
    float h1 = twox;
    float h2 = twox * h1 - 2.0f * h0;   // H_2
    float h3 = twox * h2 - 4.0f * h1;   // H_3

    float c = 6.0f;  // 2*(k-1) for k=4
    for (int it = 0; it < quad; ++it) {
        const float n0 = twox * h3 - c * h2;  // H_{4(it+1)+0}
        const float c1 = c + 2.0f;
        const float n1 = twox * n0 - c1 * h3;
        const float c2 = c + 4.0f;
        const float n2 = twox * n1 - c2 * n0;
        const float c3 = c + 6.0f;
        const float n3 = twox * n2 - c3 * n1;
        c += 8.0f;
        h0 = n0; h1 = n1; h2 = n2; h3 = n3;
    }

    // Global float4 index = blockIdx.x*256 + tid  -> wave-contiguous 1 KB.
    out4[(size_t)blockIdx.x * 256 + tid] =
        make_float4(env * h0, env * h1, env * h2, env * h3);
}

extern "C" void kernel_launch(void* const* d_in, const int* in_sizes, int n_in,
                              void* d_out, int out_size, void* d_ws, size_t ws_size,
                              hipStream_t stream) {
    const float* x     = (const float*)d_in[0];
    const float* omega = (const float*)d_in[1];
    float4* out4       = (float4*)d_out;

    const int n_rows = in_sizes[0];  // 65536 * 32 = 2,097,152

    const int rows_per_block = 32;   // 256 threads / 8 per row
    const int grid = (n_rows + rows_per_block - 1) / rows_per_block;
    hoo_kernel<<<grid, 256, 0, stream>>>(x, omega, out4, n_rows);
}

// Round 4
// 53.527 us; speedup vs baseline: 2.0572x; 1.4422x over previous
//
#include <hip/hip_runtime.h>
#include <hip/hip_bf16.h>

// HarmonicOscillatorOrbitals: out[b,i,j] = exp(-s^2/2) * H_j(s), s = x[b,i]*k
// x: (65536, 32, 1) fp32; out: (65536, 32, 32) fp32 (= 16,777,216 float4 slots).
//
// Each thread computes 4 float4 slots, strided by 256 within the block so
// every store instruction stays wave-contiguous (1 KB/wave-store):
//   slot f = blockIdx.x*1024 + k*256 + tid,  row = f>>3, quad = f&7 (= tid&7).
// 4 independent recurrence chains per thread -> 4-way VALU ILP, 4 stores in
// flight, 4x fewer waves (65536 vs 262144). Nontemporal stores: the 268 MB
// output stream exceeds the 256 MB L3, so no-allocate avoids cache thrash.
// NOTE: __builtin_nontemporal_store needs a NATIVE vector type, not HIP's
// float4 class -> use ext_vector_type(4).

#define KPT 4  // float4 slots per thread

typedef float f32x4 __attribute__((ext_vector_type(4)));

__global__ __launch_bounds__(256) void hoo_kernel(
    const float* __restrict__ x,
    const float* __restrict__ omega,
    f32x4* __restrict__ out4,
    long long n_quads)  // n_rows * 8
{
    const int tid  = threadIdx.x;
    const int quad = tid & 7;  // same for all KPT slots (256 % 8 == 0)
    const long long base = (long long)blockIdx.x * (256 * KPT) + tid;

    const float k = omega[0];

    float env[KPT], twox[KPT];
    float h0[KPT], h1[KPT], h2[KPT], h3[KPT];
    bool  ok[KPT];

#pragma unroll
    for (int kk = 0; kk < KPT; ++kk) {
        const long long f = base + (long long)kk * 256;
        ok[kk] = (f < n_quads);
        const int row = (int)(f >> 3);
        const float s = ok[kk] ? x[row] * k : 0.0f;
        env[kk]  = expf(-0.5f * (s * s));
        const float tx = 2.0f * s;
        twox[kk] = tx;
        // H_0=1, H_1=2x, H_2, H_3
        h0[kk] = 1.0f;
        h1[kk] = tx;
        h2[kk] = tx * h1[kk] - 2.0f * h0[kk];
        h3[kk] = tx * h2[kk] - 4.0f * h1[kk];
    }

    // Advance each chain by 4 Hermite orders per iteration; trip count = quad
    // (uniform across a thread's 4 chains; divergent only across lanes).
    float c = 6.0f;  // 2*(k-1) for k=4
    for (int it = 0; it < quad; ++it) {
        const float c1 = c + 2.0f;
        const float c2 = c + 4.0f;
        const float c3 = c + 6.0f;
#pragma unroll
        for (int kk = 0; kk < KPT; ++kk) {
            const float tx = twox[kk];
            const float n0 = tx * h3[kk] - c  * h2[kk];
            const float n1 = tx * n0     - c1 * h3[kk];
            const float n2 = tx * n1     - c2 * n0;
            const float n3 = tx * n2     - c3 * n1;
            h0[kk] = n0; h1[kk] = n1; h2[kk] = n2; h3[kk] = n3;
        }
        c += 8.0f;
    }

#pragma unroll
    for (int kk = 0; kk < KPT; ++kk) {
        if (ok[kk]) {
            f32x4 v;
            v.x = env[kk] * h0[kk];
            v.y = env[kk] * h1[kk];
            v.z = env[kk] * h2[kk];
            v.w = env[kk] * h3[kk];
            __builtin_nontemporal_store(v, &out4[base + (long long)kk * 256]);
        }
    }
}

extern "C" void kernel_launch(void* const* d_in, const int* in_sizes, int n_in,
                              void* d_out, int out_size, void* d_ws, size_t ws_size,
                              hipStream_t stream) {
    const float* x     = (const float*)d_in[0];
    const float* omega = (const float*)d_in[1];
    f32x4* out4        = (f32x4*)d_out;

    const long long n_rows  = in_sizes[0];      // 2,097,152
    const long long n_quads = n_rows * 8;       // 16,777,216 float4 slots

    const long long slots_per_block = 256 * KPT;  // 1024
    const int grid = (int)((n_quads + slots_per_block - 1) / slots_per_block);  // 16384
    hoo_kernel<<<grid, 256, 0, stream>>>(x, omega, out4, n_quads);
}

// Round 5
// 52.267 us; speedup vs baseline: 2.1068x; 1.0241x over previous
//
#include <hip/hip_runtime.h>
#include <hip/hip_bf16.h>

// HarmonicOscillatorOrbitals: out[b,i,j] = exp(-s^2/2) * H_j(s), s = x[b,i]*k
// x: (65536, 32, 1) fp32; out: (65536, 32, 32) fp32 (= 16,777,216 float4 slots).
//
// Thread layout: slot f = blockIdx.x*2048 + k*256 + tid, row = f>>3,
// quad = f&7 (= tid&7, invariant across k since 256 % 8 == 0).
// Every store instruction is wave-contiguous (1 KB/wave-store); each thread
// keeps 8 nontemporal float4 stores in flight (8 KB/wave, 32,768 waves).
// All slot indexing in 32-bit (max slot 16.7M << 2^31) to shrink address VALU.
// Recurrence recomputed per quad (<=7 divergent iterations/wave) - VALU ~30%
// busy, well under the write-BW bound.

#define KPT 8  // float4 slots per thread

typedef float f32x4 __attribute__((ext_vector_type(4)));

__global__ __launch_bounds__(256) void hoo_kernel(
    const float* __restrict__ x,
    const float* __restrict__ omega,
    f32x4* __restrict__ out4,
    unsigned n_quads)  // n_rows * 8
{
    const unsigned tid  = threadIdx.x;
    const unsigned quad = tid & 7;  // same for all KPT slots
    const unsigned base = blockIdx.x * (256u * KPT) + tid;

    const float k = omega[0];

    float env[KPT], twox[KPT];
    float h0[KPT], h1[KPT], h2[KPT], h3[KPT];

#pragma unroll
    for (int kk = 0; kk < KPT; ++kk) {
        const unsigned f   = base + (unsigned)kk * 256u;
        const unsigned row = (f < n_quads ? f : n_quads - 1u) >> 3;
        const float s = x[row] * k;
        env[kk]  = expf(-0.5f * (s * s));
        const float tx = 2.0f * s;
        twox[kk] = tx;
        // H_0=1, H_1=2x, H_2, H_3
        h0[kk] = 1.0f;
        h1[kk] = tx;
        h2[kk] = tx * h1[kk] - 2.0f;
        h3[kk] = tx * h2[kk] - 4.0f * h1[kk];
    }

    // Advance each chain 4 Hermite orders per iteration; trip count = quad
    // (uniform across a thread's 8 chains; divergent only across lanes).
    float c = 6.0f;  // 2*(k-1) for k=4
    for (unsigned it = 0; it < quad; ++it) {
        const float c1 = c + 2.0f;
        const float c2 = c + 4.0f;
        const float c3 = c + 6.0f;
#pragma unroll
        for (int kk = 0; kk < KPT; ++kk) {
            const float tx = twox[kk];
            const float n0 = tx * h3[kk] - c  * h2[kk];
            const float n1 = tx * n0     - c1 * h3[kk];
            const float n2 = tx * n1     - c2 * n0;
            const float n3 = tx * n2     - c3 * n1;
            h0[kk] = n0; h1[kk] = n1; h2[kk] = n2; h3[kk] = n3;
        }
        c += 8.0f;
    }

#pragma unroll
    for (int kk = 0; kk < KPT; ++kk) {
        const unsigned f = base + (unsigned)kk * 256u;
        if (f < n_quads) {
            f32x4 v;
            v.x = env[kk] * h0[kk];
            v.y = env[kk] * h1[kk];
            v.z = env[kk] * h2[kk];
            v.w = env[kk] * h3[kk];
            __builtin_nontemporal_store(v, &out4[f]);
        }
    }
}

extern "C" void kernel_launch(void* const* d_in, const int* in_sizes, int n_in,
                              void* d_out, int out_size, void* d_ws, size_t ws_size,
                              hipStream_t stream) {
    const float* x     = (const float*)d_in[0];
    const float* omega = (const float*)d_in[1];
    f32x4* out4        = (f32x4*)d_out;

    const unsigned n_rows  = (unsigned)in_sizes[0];  // 2,097,152
    const unsigned n_quads = n_rows * 8u;            // 16,777,216 float4 slots

    const unsigned slots_per_block = 256u * KPT;     // 2048
    const int grid = (int)((n_quads + slots_per_block - 1) / slots_per_block);  // 8192
    hoo_kernel<<<grid, 256, 0, stream>>>(x, omega, out4, n_quads);
}

// Round 6
// 50.420 us; speedup vs baseline: 2.1840x; 1.0366x over previous
//
#include <hip/hip_runtime.h>
#include <hip/hip_bf16.h>

// HarmonicOscillatorOrbitals: out[b,i,j] = exp(-s^2/2) * H_j(s), s = x[b,i]*k
// x: (65536, 32, 1) fp32; out: (65536, 32, 32) fp32 (= 16,777,216 float4 slots).
//
// A/B vs round 5: ONLY change is nontemporal -> regular stores.
//   - If NT was avoiding read-for-ownership, this regresses to ~77 us.
//   - If NT write-through was throttling the write stream, this improves
//     toward the ~7 TB/s fill ceiling (~45 us).
//
// Thread layout: slot f = blockIdx.x*2048 + k*256 + tid, row = f>>3,
// quad = f&7 (= tid&7, invariant across k since 256 % 8 == 0).
// Every store instruction is wave-contiguous (1 KB/wave-store); each thread
// keeps 8 float4 stores in flight. All slot indexing 32-bit.

#define KPT 8  // float4 slots per thread

typedef float f32x4 __attribute__((ext_vector_type(4)));

__global__ __launch_bounds__(256) void hoo_kernel(
    const float* __restrict__ x,
    const float* __restrict__ omega,
    f32x4* __restrict__ out4,
    unsigned n_quads)  // n_rows * 8
{
    const unsigned tid  = threadIdx.x;
    const unsigned quad = tid & 7;  // same for all KPT slots
    const unsigned base = blockIdx.x * (256u * KPT) + tid;

    const float k = omega[0];

    float env[KPT], twox[KPT];
    float h0[KPT], h1[KPT], h2[KPT], h3[KPT];

#pragma unroll
    for (int kk = 0; kk < KPT; ++kk) {
        const unsigned f   = base + (unsigned)kk * 256u;
        const unsigned row = (f < n_quads ? f : n_quads - 1u) >> 3;
        const float s = x[row] * k;
        env[kk]  = expf(-0.5f * (s * s));
        const float tx = 2.0f * s;
        twox[kk] = tx;
        // H_0=1, H_1=2x, H_2, H_3
        h0[kk] = 1.0f;
        h1[kk] = tx;
        h2[kk] = tx * h1[kk] - 2.0f;
        h3[kk] = tx * h2[kk] - 4.0f * h1[kk];
    }

    // Advance each chain 4 Hermite orders per iteration; trip count = quad
    // (uniform across a thread's 8 chains; divergent only across lanes).
    float c = 6.0f;  // 2*(k-1) for k=4
    for (unsigned it = 0; it < quad; ++it) {
        const float c1 = c + 2.0f;
        const float c2 = c + 4.0f;
        const float c3 = c + 6.0f;
#pragma unroll
        for (int kk = 0; kk < KPT; ++kk) {
            const float tx = twox[kk];
            const float n0 = tx * h3[kk] - c  * h2[kk];
            const float n1 = tx * n0     - c1 * h3[kk];
            const float n2 = tx * n1     - c2 * n0;
            const float n3 = tx * n2     - c3 * n1;
            h0[kk] = n0; h1[kk] = n1; h2[kk] = n2; h3[kk] = n3;
        }
        c += 8.0f;
    }

#pragma unroll
    for (int kk = 0; kk < KPT; ++kk) {
        const unsigned f = base + (unsigned)kk * 256u;
        if (f < n_quads) {
            f32x4 v;
            v.x = env[kk] * h0[kk];
            v.y = env[kk] * h1[kk];
            v.z = env[kk] * h2[kk];
            v.w = env[kk] * h3[kk];
            out4[f] = v;  // regular (write-back) store — the only change
        }
    }
}

extern "C" void kernel_launch(void* const* d_in, const int* in_sizes, int n_in,
                              void* d_out, int out_size, void* d_ws, size_t ws_size,
                              hipStream_t stream) {
    const float* x     = (const float*)d_in[0];
    const float* omega = (const float*)d_in[1];
    f32x4* out4        = (f32x4*)d_out;

    const unsigned n_rows  = (unsigned)in_sizes[0];  // 2,097,152
    const unsigned n_quads = n_rows * 8u;            // 16,777,216 float4 slots

    const unsigned slots_per_block = 256u * KPT;     // 2048
    const int grid = (int)((n_quads + slots_per_block - 1) / slots_per_block);  // 8192
    hoo_kernel<<<grid, 256, 0, stream>>>(x, omega, out4, n_quads);
}